// Round 1
// 240.205 us; speedup vs baseline: 1.0656x; 1.0656x over previous
//
#include <hip/hip_runtime.h>
#include <math.h>

// QuantumNeuralNetwork: 12-qubit, 16-layer RY+CNOT-ring state-vector sim.
// Round 10: round-9 structure (256 thr/block, 16 complex amps/lane as float2,
// packed gates, b64 LDS trips under bank-proven slot map F, 3 barriers/layer)
// with per-gate trig REMOVED from the hot loop. Previously every lane computed
// 12 identical __cosf/__sinf pairs per layer (v_cos/v_sin are quarter-rate:
// ~264 VALU-cyc/layer ~= 18% of VALU execution). Now each wave builds the full
// 16x12 (cos,sin) table once at entry (lanes 0..47 compute 4 pairs each into
// 8 VGPRs), and each gate broadcasts its pair via v_readlane_b32:
//   value for (layer l, gate g) lives in reg (g&3), lane l + 16*(g>>2)
// Both indices are compile-time-safe (reg idx literal, lane idx uniform SGPR).
// Extraction ~48 cyc/layer vs 264 removed; no LDS/occupancy cost.
//
// Bank-proven slot map F (GF(2)-linear, bijective), verified rounds 6-9:
//   s[3:0] = x[7:4] ^ Q(x[3:0]),  s[7:4] = x[3:0],  s[11:8] = x[11:8]
//   Q: q0=n0^n3, q1=n1^n3, q2=n2, q3=n0   (invertible)
// Gate placement (verified rounds 6-9):
//   L1: amp=(t<<4)|r. q8..q11 reg (masks 8,4,2,1); q7 dpp xor1 (0xB1);
//       q6 dpp xor2 (0x4E); q5 ds_swizzle xor4 (0x101F); q4 dpp row_ror:8.
//   trip1 -> L2: amp=(r<<8)|t. q0..q3 reg (masks 8,4,2,1)
//   trip2 -> L1 fused with CNOT-ring perm G(i)=i^(i>>1)^(i0?0xC00:0).

#define DIM     4096
#define NLAYERS 16
#define BATCH   2048
#define NCLASS  5

typedef float v2f __attribute__((ext_vector_type(2)));

__host__ __device__ constexpr unsigned gperm(unsigned i) {
  for (int q = 11; q >= 0; --q) {
    const unsigned cbit = 1u << (11 - q);
    const unsigned tbit = 1u << (11 - ((q + 1) % 12));
    if (i & cbit) i ^= tbit;
  }
  return i;
}
// Q and F: the bank-proven slot map (see header comment)
__host__ __device__ constexpr unsigned Qmap(unsigned lo) {
  return ((lo ^ (lo >> 3)) & 1u) | ((((lo >> 1) ^ (lo >> 3)) & 1u) << 1) |
         (((lo >> 2) & 1u) << 2) | ((lo & 1u) << 3);
}
__host__ __device__ constexpr unsigned Fmap(unsigned x) {
  return (x & 0xF00u) | ((x & 0xFu) << 4) | (((x >> 4) & 0xFu) ^ Qmap(x & 0xFu));
}

// DPP lane permutes (VALU): 0xB1 quad xor1, 0x4E quad xor2, 0x128 row_ror:8
template<int CTRL>
__device__ __forceinline__ float dppf(float x) {
  return __int_as_float(__builtin_amdgcn_update_dpp(
      0, __float_as_int(x), CTRL, 0xF, 0xF, true));
}
// ds_swizzle lane-xor (LDS pipe, no barrier): 0x101F = xor4
template<int PAT>
__device__ __forceinline__ float swzf(float x) {
  return __int_as_float(__builtin_amdgcn_ds_swizzle(__float_as_int(x), PAT));
}

#define FOR16(M) M(0) M(1) M(2) M(3) M(4) M(5) M(6) M(7) M(8) M(9) M(10) \
  M(11) M(12) M(13) M(14) M(15)

// packed RY pair-rotation (uses v2f locals cv, sv, nsv in scope)
#define ROT(i, j) {                                          \
    const v2f ti = p##i, tj = p##j;                          \
    p##i = __builtin_elementwise_fma(nsv, tj, cv * ti);      \
    p##j = __builtin_elementwise_fma(sv,  ti, cv * tj); }

#define GM8 ROT(0,8) ROT(1,9) ROT(2,10) ROT(3,11) ROT(4,12) ROT(5,13) \
  ROT(6,14) ROT(7,15)
#define GM4 ROT(0,4) ROT(1,5) ROT(2,6) ROT(3,7) ROT(8,12) ROT(9,13) \
  ROT(10,14) ROT(11,15)
#define GM2 ROT(0,2) ROT(1,3) ROT(4,6) ROT(5,7) ROT(8,10) ROT(9,11) \
  ROT(12,14) ROT(13,15)
#define GM1 ROT(0,1) ROT(2,3) ROT(4,5) ROT(6,7) ROT(8,9) ROT(10,11) \
  ROT(12,13) ROT(14,15)

// broadcast (cos,sin) for (layer l, gate g) from the per-wave trig table:
// reg = g&3 (literal), lane = l + 16*(g>>2) (uniform SGPR)
#define GETCS(g) \
  const float cG = __int_as_float(__builtin_amdgcn_readlane( \
      __float_as_int(vcg[(g) & 3]), l + (((g) >> 2) << 4))); \
  const float sG = __int_as_float(__builtin_amdgcn_readlane( \
      __float_as_int(vsg[(g) & 3]), l + (((g) >> 2) << 4)));

__global__ __launch_bounds__(256)
void qnn_sim(const float* __restrict__ zr, const float* __restrict__ zi,
             const float* __restrict__ thetas, const int* __restrict__ y,
             float* __restrict__ out) {
  __shared__ v2f buf2[DIM];  // 32 KB: (re,im) per amp, slot = F(amp)
  const int b = blockIdx.x;
  const int t = threadIdx.x;  // 0..255

  // layer-invariant bases under F
  const int w1b = (int)((((unsigned)t & 0xF0u) << 4) | ((unsigned)t & 0xFu)); // F(t<<4)
  const int r1b = (int)Fmap((unsigned)t);                                      // F(t)
  const int Gt  = ((t << 4) ^ (t << 3)) & 0xFFF;                               // G(t<<4)
  const int r2b = (int)Fmap((unsigned)Gt);                                     // F(G(t<<4))

  v2f p0,p1,p2,p3,p4,p5,p6,p7,p8,p9,p10,p11,p12,p13,p14,p15;
  {
    const float4* zr4 = (const float4*)(zr + (size_t)b * DIM + (t << 4));
    const float4* zi4 = (const float4*)(zi + (size_t)b * DIM + (t << 4));
    const float4 a0 = zr4[0], a1 = zr4[1], a2 = zr4[2], a3 = zr4[3];
    const float4 b0 = zi4[0], b1 = zi4[1], b2 = zi4[2], b3 = zi4[3];
    p0  = (v2f){a0.x, b0.x}; p1  = (v2f){a0.y, b0.y};
    p2  = (v2f){a0.z, b0.z}; p3  = (v2f){a0.w, b0.w};
    p4  = (v2f){a1.x, b1.x}; p5  = (v2f){a1.y, b1.y};
    p6  = (v2f){a1.z, b1.z}; p7  = (v2f){a1.w, b1.w};
    p8  = (v2f){a2.x, b2.x}; p9  = (v2f){a2.y, b2.y};
    p10 = (v2f){a2.z, b2.z}; p11 = (v2f){a2.w, b2.w};
    p12 = (v2f){a3.x, b3.x}; p13 = (v2f){a3.y, b3.y};
    p14 = (v2f){a3.z, b3.z}; p15 = (v2f){a3.w, b3.w};
  }

  // ---- per-wave trig table (once): lane (l + 16*(g>>2)), reg (g&3) holds
  // cos/sin(theta[l][g]/2). Lanes 48..63 compute a clamped duplicate (unused).
  float vcg[4], vsg[4];
  {
    const int lane = t & 63;
    const int lsrc = lane & 15;          // source layer
    const int gb = (lane >> 4) << 2;     // gate group base: 0,4,8,(12->clamp)
#pragma unroll
    for (int j = 0; j < 4; ++j) {
      int g = gb + j; g = (g > 11) ? 11 : g;
      const float a = 0.5f * thetas[lsrc * 12 + g];
      vcg[j] = cosf(a);
      vsg[j] = sinf(a);
    }
  }

#pragma unroll 1
  for (int l = 0; l < NLAYERS; ++l) {
    // ---- L1 register gates: q8..q11 (amp bits 3..0 -> masks 8,4,2,1) ----
    { GETCS(8)  const v2f cv = {cG,cG}, sv = {sG,sG}, nsv = {-sG,-sG}; GM8 }
    { GETCS(9)  const v2f cv = {cG,cG}, sv = {sG,sG}, nsv = {-sG,-sG}; GM4 }
    { GETCS(10) const v2f cv = {cG,cG}, sv = {sG,sG}, nsv = {-sG,-sG}; GM2 }
    { GETCS(11) const v2f cv = {cG,cG}, sv = {sG,sG}, nsv = {-sG,-sG}; GM1 }

    // ---- DPP gates: q7 (t0, xor1), q6 (t1, xor2), q4 (t3, row_ror:8) ----
    {
      GETCS(7)
      const float sg7 = (t & 1) ? sG : -sG;
      const v2f cv = {cG,cG}, ssv = {sg7,sg7};
#define DPPG7(i) { v2f pr; pr.x = dppf<0xB1>(p##i.x); pr.y = dppf<0xB1>(p##i.y); \
      p##i = __builtin_elementwise_fma(ssv, pr, cv * p##i); }
      FOR16(DPPG7)
#undef DPPG7
    }
    {
      GETCS(6)
      const float sg6 = (t & 2) ? sG : -sG;
      const v2f cv = {cG,cG}, ssv = {sg6,sg6};
#define DPPG6(i) { v2f pr; pr.x = dppf<0x4E>(p##i.x); pr.y = dppf<0x4E>(p##i.y); \
      p##i = __builtin_elementwise_fma(ssv, pr, cv * p##i); }
      FOR16(DPPG6)
#undef DPPG6
    }
    {
      GETCS(4)
      const float sg4 = (t & 8) ? sG : -sG;
      const v2f cv = {cG,cG}, ssv = {sg4,sg4};
#define DPPG4(i) { v2f pr; pr.x = dppf<0x128>(p##i.x); pr.y = dppf<0x128>(p##i.y); \
      p##i = __builtin_elementwise_fma(ssv, pr, cv * p##i); }
      FOR16(DPPG4)
#undef DPPG4
    }

    // ---- swizzle gate: q5 (amp bit6 = t2, xor4) ----
    {
      GETCS(5)
      const float sg5 = (t & 4) ? sG : -sG;
      const v2f cv = {cG,cG}, ssv = {sg5,sg5};
#define SWG5(i) { v2f pr; pr.x = swzf<0x101F>(p##i.x); pr.y = swzf<0x101F>(p##i.y); \
      p##i = __builtin_elementwise_fma(ssv, pr, cv * p##i); }
      FOR16(SWG5)
#undef SWG5
    }

    // ---- trip 1: L1 -> L2 (b64, slot = F(amp)) ----
    __syncthreads();  // prev layer's R2 reads done
#define W1P(i) buf2[w1b ^ (int)Fmap((unsigned)i)] = p##i;
    FOR16(W1P)
#undef W1P
    __syncthreads();
#define R1P(i) p##i = buf2[r1b + (i << 8)];
    FOR16(R1P)
#undef R1P

    // ---- L2 register gates: q0..q3 (amp bits 11..8 -> masks 8,4,2,1) ----
    { GETCS(0) const v2f cv = {cG,cG}, sv = {sG,sG}, nsv = {-sG,-sG}; GM8 }
    { GETCS(1) const v2f cv = {cG,cG}, sv = {sG,sG}, nsv = {-sG,-sG}; GM4 }
    { GETCS(2) const v2f cv = {cG,cG}, sv = {sG,sG}, nsv = {-sG,-sG}; GM2 }
    { GETCS(3) const v2f cv = {cG,cG}, sv = {sG,sG}, nsv = {-sG,-sG}; GM1 }

    // ---- trip 2: L2 -> L1 fused with CNOT-ring gather ----
    // NO barrier before W2: each thread writes exactly the addresses it
    // read in R1 (bijective per-thread sets -> no cross-thread hazard).
#define W2P(i) buf2[r1b + (i << 8)] = p##i;
    FOR16(W2P)
#undef W2P
    __syncthreads();
#define R2P(i) p##i = buf2[r2b ^ (int)Fmap(gperm((unsigned)i))];
    FOR16(R2P)
#undef R2P
  }

  // ---- Z expectations: wire w sign = amp bit (11-w) = t bit (7-w) ----
  float P = 0.f;
#define ACC(i) P = __builtin_fmaf(p##i.x, p##i.x, P); \
               P = __builtin_fmaf(p##i.y, p##i.y, P);
  FOR16(ACC)
#undef ACC
  float e0 = ((t >> 7) & 1) ? -P : P;
  float e1 = ((t >> 6) & 1) ? -P : P;
  float e2 = ((t >> 5) & 1) ? -P : P;
  float e3 = ((t >> 4) & 1) ? -P : P;
  float e4 = ((t >> 3) & 1) ? -P : P;
#pragma unroll
  for (int off = 32; off >= 1; off >>= 1) {
    e0 += __shfl_xor(e0, off);
    e1 += __shfl_xor(e1, off);
    e2 += __shfl_xor(e2, off);
    e3 += __shfl_xor(e3, off);
    e4 += __shfl_xor(e4, off);
  }
  float* bf = (float*)buf2;
  __syncthreads();  // last R2 reads done before buf reuse
  if ((t & 63) == 0) {
    const int w8 = (t >> 6) * 8;
    bf[w8 + 0] = e0; bf[w8 + 1] = e1; bf[w8 + 2] = e2;
    bf[w8 + 3] = e3; bf[w8 + 4] = e4;
  }
  __syncthreads();
  if (t == 0) {
    const float o0 = bf[0] + bf[8]  + bf[16] + bf[24];
    const float o1 = bf[1] + bf[9]  + bf[17] + bf[25];
    const float o2 = bf[2] + bf[10] + bf[18] + bf[26];
    const float o3 = bf[3] + bf[11] + bf[19] + bf[27];
    const float o4 = bf[4] + bf[12] + bf[20] + bf[28];
    float* op = out + 1 + (size_t)b * NCLASS;
    op[0] = o0; op[1] = o1; op[2] = o2; op[3] = o3; op[4] = o4;
    // fused NLL: loss contribution = (logsumexp(o) - o[y]) / BATCH
    const float m = fmaxf(fmaxf(fmaxf(o0, o1), fmaxf(o2, o3)), o4);
    const float sum = expf(o0 - m) + expf(o1 - m) + expf(o2 - m) +
                      expf(o3 - m) + expf(o4 - m);
    const int yb = y[b];
    const float oy = (yb == 0) ? o0 : (yb == 1) ? o1 : (yb == 2) ? o2
                   : (yb == 3) ? o3 : o4;
    const float nll = (m + logf(sum)) - oy;
    atomicAdd(out, nll * (1.0f / BATCH));
  }
}

extern "C" void kernel_launch(void* const* d_in, const int* in_sizes, int n_in,
                              void* d_out, int out_size, void* d_ws, size_t ws_size,
                              hipStream_t stream) {
  const float* zr = (const float*)d_in[0];
  const float* zi = (const float*)d_in[1];
  const float* th = (const float*)d_in[2];
  const int*   y  = (const int*)d_in[3];
  float* out = (float*)d_out;
  hipMemsetAsync(out, 0, sizeof(float), stream);  // zero loss accumulator
  qnn_sim<<<BATCH, 256, 0, stream>>>(zr, zi, th, y, out);
}

// Round 2
// 217.267 us; speedup vs baseline: 1.1781x; 1.1056x over previous
//
#include <hip/hip_runtime.h>
#include <math.h>

// QuantumNeuralNetwork: 12-qubit, 16-layer RY+CNOT-ring state-vector sim.
// Round 11: round-10 structure (256 thr/block, 16 amps/lane as float2, packed
// gates, b64 LDS trips under bank-proven slot map F, 3 barriers/layer, per-wave
// trig table + readlane broadcast) with the RY gates TAN-FACTORED:
//   RY(th) = c * [[1, -k],[k, 1]],  k = tan(th/2) = s/c
// The shear costs 2 pk_fma per ROT (vs 2 pk_mul + 2 pk_fma for the rotation);
// the scalar c factors out of the whole layer and is applied as two uniform
// 16-amp scales per layer: CA = prod c(q4..q11) fused into the q5 gate,
// CB = prod c(q0..q3) applied before trip 2. ~33% fewer VALU issue slots.
// Numerics: |k| <= ~5.5 for N(0,1) thetas; CA/CB split keeps within-segment
// amplitude growth small, so rounding stays within tolerance.
// Trig table (built once per wave, 4 VGPRs):
//   lanes 0..47: vkg[j] = k for (layer = lane&15, gate = 4*(lane>>4)+j)
//   lanes 48..63: vkg[0] = CA(layer = lane-48), vkg[1] = CB(layer)
//
// Bank-proven slot map F (GF(2)-linear, bijective), verified rounds 6-10:
//   s[3:0] = x[7:4] ^ Q(x[3:0]),  s[7:4] = x[3:0],  s[11:8] = x[11:8]
//   Q: q0=n0^n3, q1=n1^n3, q2=n2, q3=n0   (invertible)
// Gate placement (verified rounds 6-10):
//   L1: amp=(t<<4)|r. q8..q11 reg (masks 8,4,2,1); q7 dpp xor1 (0xB1);
//       q6 dpp xor2 (0x4E); q5 ds_swizzle xor4 (0x101F); q4 dpp row_ror:8.
//   trip1 -> L2: amp=(r<<8)|t. q0..q3 reg (masks 8,4,2,1)
//   trip2 -> L1 fused with CNOT-ring perm G(i)=i^(i>>1)^(i0?0xC00:0).

#define DIM     4096
#define NLAYERS 16
#define BATCH   2048
#define NCLASS  5

typedef float v2f __attribute__((ext_vector_type(2)));

__host__ __device__ constexpr unsigned gperm(unsigned i) {
  for (int q = 11; q >= 0; --q) {
    const unsigned cbit = 1u << (11 - q);
    const unsigned tbit = 1u << (11 - ((q + 1) % 12));
    if (i & cbit) i ^= tbit;
  }
  return i;
}
// Q and F: the bank-proven slot map (see header comment)
__host__ __device__ constexpr unsigned Qmap(unsigned lo) {
  return ((lo ^ (lo >> 3)) & 1u) | ((((lo >> 1) ^ (lo >> 3)) & 1u) << 1) |
         (((lo >> 2) & 1u) << 2) | ((lo & 1u) << 3);
}
__host__ __device__ constexpr unsigned Fmap(unsigned x) {
  return (x & 0xF00u) | ((x & 0xFu) << 4) | (((x >> 4) & 0xFu) ^ Qmap(x & 0xFu));
}

// DPP lane permutes (VALU): 0xB1 quad xor1, 0x4E quad xor2, 0x128 row_ror:8
template<int CTRL>
__device__ __forceinline__ float dppf(float x) {
  return __int_as_float(__builtin_amdgcn_update_dpp(
      0, __float_as_int(x), CTRL, 0xF, 0xF, true));
}
// ds_swizzle lane-xor (LDS pipe, no barrier): 0x101F = xor4
template<int PAT>
__device__ __forceinline__ float swzf(float x) {
  return __int_as_float(__builtin_amdgcn_ds_swizzle(__float_as_int(x), PAT));
}

#define FOR16(M) M(0) M(1) M(2) M(3) M(4) M(5) M(6) M(7) M(8) M(9) M(10) \
  M(11) M(12) M(13) M(14) M(15)

// packed shear pair-rotation (uses v2f locals kv, nkv in scope):
//   pi' = pi - k*pj ; pj' = pj + k*pi   (scalar c deferred to CA/CB)
#define ROT(i, j) {                                          \
    const v2f ti = p##i, tj = p##j;                          \
    p##i = __builtin_elementwise_fma(nkv, tj, ti);           \
    p##j = __builtin_elementwise_fma(kv,  ti, tj); }

#define GM8 ROT(0,8) ROT(1,9) ROT(2,10) ROT(3,11) ROT(4,12) ROT(5,13) \
  ROT(6,14) ROT(7,15)
#define GM4 ROT(0,4) ROT(1,5) ROT(2,6) ROT(3,7) ROT(8,12) ROT(9,13) \
  ROT(10,14) ROT(11,15)
#define GM2 ROT(0,2) ROT(1,3) ROT(4,6) ROT(5,7) ROT(8,10) ROT(9,11) \
  ROT(12,14) ROT(13,15)
#define GM1 ROT(0,1) ROT(2,3) ROT(4,5) ROT(6,7) ROT(8,9) ROT(10,11) \
  ROT(12,13) ROT(14,15)

// broadcast k for (layer l, gate g) from the per-wave trig table:
// reg = g&3 (literal), lane = l + 16*(g>>2) (uniform SGPR)
#define GETK(g) \
  const float kG = __int_as_float(__builtin_amdgcn_readlane( \
      __float_as_int(vkg[(g) & 3]), l + (((g) >> 2) << 4)));

__global__ __launch_bounds__(256)
void qnn_sim(const float* __restrict__ zr, const float* __restrict__ zi,
             const float* __restrict__ thetas, const int* __restrict__ y,
             float* __restrict__ out) {
  __shared__ v2f buf2[DIM];  // 32 KB: (re,im) per amp, slot = F(amp)
  const int b = blockIdx.x;
  const int t = threadIdx.x;  // 0..255

  // layer-invariant bases under F
  const int w1b = (int)((((unsigned)t & 0xF0u) << 4) | ((unsigned)t & 0xFu)); // F(t<<4)
  const int r1b = (int)Fmap((unsigned)t);                                      // F(t)
  const int Gt  = ((t << 4) ^ (t << 3)) & 0xFFF;                               // G(t<<4)
  const int r2b = (int)Fmap((unsigned)Gt);                                     // F(G(t<<4))

  v2f p0,p1,p2,p3,p4,p5,p6,p7,p8,p9,p10,p11,p12,p13,p14,p15;
  {
    const float4* zr4 = (const float4*)(zr + (size_t)b * DIM + (t << 4));
    const float4* zi4 = (const float4*)(zi + (size_t)b * DIM + (t << 4));
    const float4 a0 = zr4[0], a1 = zr4[1], a2 = zr4[2], a3 = zr4[3];
    const float4 b0 = zi4[0], b1 = zi4[1], b2 = zi4[2], b3 = zi4[3];
    p0  = (v2f){a0.x, b0.x}; p1  = (v2f){a0.y, b0.y};
    p2  = (v2f){a0.z, b0.z}; p3  = (v2f){a0.w, b0.w};
    p4  = (v2f){a1.x, b1.x}; p5  = (v2f){a1.y, b1.y};
    p6  = (v2f){a1.z, b1.z}; p7  = (v2f){a1.w, b1.w};
    p8  = (v2f){a2.x, b2.x}; p9  = (v2f){a2.y, b2.y};
    p10 = (v2f){a2.z, b2.z}; p11 = (v2f){a2.w, b2.w};
    p12 = (v2f){a3.x, b3.x}; p13 = (v2f){a3.y, b3.y};
    p14 = (v2f){a3.z, b3.z}; p15 = (v2f){a3.w, b3.w};
  }

  // ---- per-wave trig table (once), 4 VGPRs:
  // lanes 0..47:  vkg[j] = tan(theta[lane&15][4*(lane>>4)+j] / 2)
  // lanes 48..63: vkg[0] = CA = prod_{g=4..11} cos(th/2)   (layer = lane-48)
  //               vkg[1] = CB = prod_{g=0..3}  cos(th/2)
  float vkg[4];
  {
    const int lane = t & 63;
    if (lane < 48) {
      const int lsrc = lane & 15;          // source layer
      const int gb = (lane >> 4) << 2;     // gate group base: 0, 4, 8
#pragma unroll
      for (int j = 0; j < 4; ++j) {
        const float a = 0.5f * thetas[lsrc * 12 + gb + j];
        vkg[j] = sinf(a) / cosf(a);
      }
    } else {
      const int lsrc = lane - 48;
      float ca = 1.f, cb = 1.f;
      for (int g = 0; g < 4; ++g)  cb *= cosf(0.5f * thetas[lsrc * 12 + g]);
      for (int g = 4; g < 12; ++g) ca *= cosf(0.5f * thetas[lsrc * 12 + g]);
      vkg[0] = ca; vkg[1] = cb; vkg[2] = 0.f; vkg[3] = 0.f;
    }
  }

#pragma unroll 1
  for (int l = 0; l < NLAYERS; ++l) {
    // per-layer deferred cosine products
    const float CA = __int_as_float(__builtin_amdgcn_readlane(
        __float_as_int(vkg[0]), 48 + l));
    const float CB = __int_as_float(__builtin_amdgcn_readlane(
        __float_as_int(vkg[1]), 48 + l));

    // ---- L1 register gates: q8..q11 (amp bits 3..0 -> masks 8,4,2,1) ----
    { GETK(8)  const v2f kv = {kG,kG}, nkv = {-kG,-kG}; GM8 }
    { GETK(9)  const v2f kv = {kG,kG}, nkv = {-kG,-kG}; GM4 }
    { GETK(10) const v2f kv = {kG,kG}, nkv = {-kG,-kG}; GM2 }
    { GETK(11) const v2f kv = {kG,kG}, nkv = {-kG,-kG}; GM1 }

    // ---- DPP gates: q7 (t0, xor1), q6 (t1, xor2), q4 (t3, row_ror:8) ----
    {
      GETK(7)
      const float sg7 = (t & 1) ? kG : -kG;
      const v2f skv = {sg7,sg7};
#define DPPG7(i) { v2f pr; pr.x = dppf<0xB1>(p##i.x); pr.y = dppf<0xB1>(p##i.y); \
      p##i = __builtin_elementwise_fma(skv, pr, p##i); }
      FOR16(DPPG7)
#undef DPPG7
    }
    {
      GETK(6)
      const float sg6 = (t & 2) ? kG : -kG;
      const v2f skv = {sg6,sg6};
#define DPPG6(i) { v2f pr; pr.x = dppf<0x4E>(p##i.x); pr.y = dppf<0x4E>(p##i.y); \
      p##i = __builtin_elementwise_fma(skv, pr, p##i); }
      FOR16(DPPG6)
#undef DPPG6
    }
    {
      GETK(4)
      const float sg4 = (t & 8) ? kG : -kG;
      const v2f skv = {sg4,sg4};
#define DPPG4(i) { v2f pr; pr.x = dppf<0x128>(p##i.x); pr.y = dppf<0x128>(p##i.y); \
      p##i = __builtin_elementwise_fma(skv, pr, p##i); }
      FOR16(DPPG4)
#undef DPPG4
    }

    // ---- swizzle gate: q5 (amp bit6 = t2, xor4), fused with CA scale ----
    {
      GETK(5)
      const float sg5 = (t & 4) ? kG : -kG;
      const v2f skv = {sg5,sg5}, cav = {CA,CA};
#define SWG5(i) { v2f pr; pr.x = swzf<0x101F>(p##i.x); pr.y = swzf<0x101F>(p##i.y); \
      p##i = cav * __builtin_elementwise_fma(skv, pr, p##i); }
      FOR16(SWG5)
#undef SWG5
    }

    // ---- trip 1: L1 -> L2 (b64, slot = F(amp)) ----
    __syncthreads();  // prev layer's R2 reads done
#define W1P(i) buf2[w1b ^ (int)Fmap((unsigned)i)] = p##i;
    FOR16(W1P)
#undef W1P
    __syncthreads();
#define R1P(i) p##i = buf2[r1b + (i << 8)];
    FOR16(R1P)
#undef R1P

    // ---- L2 register gates: q0..q3 (amp bits 11..8 -> masks 8,4,2,1) ----
    { GETK(0) const v2f kv = {kG,kG}, nkv = {-kG,-kG}; GM8 }
    { GETK(1) const v2f kv = {kG,kG}, nkv = {-kG,-kG}; GM4 }
    { GETK(2) const v2f kv = {kG,kG}, nkv = {-kG,-kG}; GM2 }
    { GETK(3) const v2f kv = {kG,kG}, nkv = {-kG,-kG}; GM1 }

    // ---- deferred CB scale for q0..q3 ----
    {
      const v2f cbv = {CB,CB};
#define SCB(i) p##i = cbv * p##i;
      FOR16(SCB)
#undef SCB
    }

    // ---- trip 2: L2 -> L1 fused with CNOT-ring gather ----
    // NO barrier before W2: each thread writes exactly the addresses it
    // read in R1 (bijective per-thread sets -> no cross-thread hazard).
#define W2P(i) buf2[r1b + (i << 8)] = p##i;
    FOR16(W2P)
#undef W2P
    __syncthreads();
#define R2P(i) p##i = buf2[r2b ^ (int)Fmap(gperm((unsigned)i))];
    FOR16(R2P)
#undef R2P
  }

  // ---- Z expectations: wire w sign = amp bit (11-w) = t bit (7-w) ----
  float P = 0.f;
#define ACC(i) P = __builtin_fmaf(p##i.x, p##i.x, P); \
               P = __builtin_fmaf(p##i.y, p##i.y, P);
  FOR16(ACC)
#undef ACC
  float e0 = ((t >> 7) & 1) ? -P : P;
  float e1 = ((t >> 6) & 1) ? -P : P;
  float e2 = ((t >> 5) & 1) ? -P : P;
  float e3 = ((t >> 4) & 1) ? -P : P;
  float e4 = ((t >> 3) & 1) ? -P : P;
#pragma unroll
  for (int off = 32; off >= 1; off >>= 1) {
    e0 += __shfl_xor(e0, off);
    e1 += __shfl_xor(e1, off);
    e2 += __shfl_xor(e2, off);
    e3 += __shfl_xor(e3, off);
    e4 += __shfl_xor(e4, off);
  }
  float* bf = (float*)buf2;
  __syncthreads();  // last R2 reads done before buf reuse
  if ((t & 63) == 0) {
    const int w8 = (t >> 6) * 8;
    bf[w8 + 0] = e0; bf[w8 + 1] = e1; bf[w8 + 2] = e2;
    bf[w8 + 3] = e3; bf[w8 + 4] = e4;
  }
  __syncthreads();
  if (t == 0) {
    const float o0 = bf[0] + bf[8]  + bf[16] + bf[24];
    const float o1 = bf[1] + bf[9]  + bf[17] + bf[25];
    const float o2 = bf[2] + bf[10] + bf[18] + bf[26];
    const float o3 = bf[3] + bf[11] + bf[19] + bf[27];
    const float o4 = bf[4] + bf[12] + bf[20] + bf[28];
    float* op = out + 1 + (size_t)b * NCLASS;
    op[0] = o0; op[1] = o1; op[2] = o2; op[3] = o3; op[4] = o4;
    // fused NLL: loss contribution = (logsumexp(o) - o[y]) / BATCH
    const float m = fmaxf(fmaxf(fmaxf(o0, o1), fmaxf(o2, o3)), o4);
    const float sum = expf(o0 - m) + expf(o1 - m) + expf(o2 - m) +
                      expf(o3 - m) + expf(o4 - m);
    const int yb = y[b];
    const float oy = (yb == 0) ? o0 : (yb == 1) ? o1 : (yb == 2) ? o2
                   : (yb == 3) ? o3 : o4;
    const float nll = (m + logf(sum)) - oy;
    atomicAdd(out, nll * (1.0f / BATCH));
  }
}

extern "C" void kernel_launch(void* const* d_in, const int* in_sizes, int n_in,
                              void* d_out, int out_size, void* d_ws, size_t ws_size,
                              hipStream_t stream) {
  const float* zr = (const float*)d_in[0];
  const float* zi = (const float*)d_in[1];
  const float* th = (const float*)d_in[2];
  const int*   y  = (const int*)d_in[3];
  float* out = (float*)d_out;
  hipMemsetAsync(out, 0, sizeof(float), stream);  // zero loss accumulator
  qnn_sim<<<BATCH, 256, 0, stream>>>(zr, zi, th, y, out);
}

// Round 3
// 215.171 us; speedup vs baseline: 1.1896x; 1.0097x over previous
//
#include <hip/hip_runtime.h>
#include <math.h>

// QuantumNeuralNetwork: 12-qubit, 16-layer RY+CNOT-ring state-vector sim.
// Round 12: round-11 structure (256 thr/block, 16 amps/lane as float2, tan-
// factored shears, per-wave trig table + readlane broadcast, b64 LDS trips
// under bank-proven slot map F, 3 barriers/layer) with the per-layer q5
// ds_swizzle gate ELIMINATED via R2 partner-fold:
//   q5 pairs amp bit 6; post-perm amp y=(t<<4)|i partners with y^0x40 held by
//   thread t^4. At R2 time both live in LDS: partner slot = primary ^ 0x006
//   (F(G(0x40)) = 0x006, F and G GF(2)-linear). Layer l's R2 applies layer
//   l+1's q5 as 16 extra b64 reads + 16 pk_fma. The pre-W1 barrier already
//   protects these reads (fold into R1 would race with barrier-free W2:
//   partner slots of thread t are primary slots of thread t^64, another wave).
//   Layer 0's q5 runs once as a swizzle pass before the loop.
// Also: CA/CB merged into one per-layer C pass (16 pk_mul, amplitude stays ~1,
// no overflow risk), W1/R2 addresses hoisted out of the loop (layer-invariant).
// DS issues/lane/layer: 96 -> 80, bank conflicts -> init-only (262K total).
//
// Bank-proven slot map F (GF(2)-linear, bijective), verified rounds 6-11:
//   s[3:0] = x[7:4] ^ Q(x[3:0]),  s[7:4] = x[3:0],  s[11:8] = x[11:8]
//   Q: q0=n0^n3, q1=n1^n3, q2=n2, q3=n0   (invertible)
// Partner addressing keeps the per-16-lane-group slot[3:0] bijectivity (XOR
// by the constant 0x6 preserves bijections).
// Gate placement (verified rounds 6-11):
//   L1: amp=(t<<4)|r. q8..q11 reg (masks 8,4,2,1); q7 dpp xor1 (0xB1);
//       q6 dpp xor2 (0x4E); q4 dpp row_ror:8. q5: R2-folded (see above).
//   trip1 -> L2: amp=(r<<8)|t. q0..q3 reg (masks 8,4,2,1)
//   trip2 -> L1 fused with CNOT-ring perm G(i)=i^(i>>1)^(i0?0xC00:0).

#define DIM     4096
#define NLAYERS 16
#define BATCH   2048
#define NCLASS  5

typedef float v2f __attribute__((ext_vector_type(2)));

__host__ __device__ constexpr unsigned gperm(unsigned i) {
  for (int q = 11; q >= 0; --q) {
    const unsigned cbit = 1u << (11 - q);
    const unsigned tbit = 1u << (11 - ((q + 1) % 12));
    if (i & cbit) i ^= tbit;
  }
  return i;
}
// Q and F: the bank-proven slot map (see header comment)
__host__ __device__ constexpr unsigned Qmap(unsigned lo) {
  return ((lo ^ (lo >> 3)) & 1u) | ((((lo >> 1) ^ (lo >> 3)) & 1u) << 1) |
         (((lo >> 2) & 1u) << 2) | ((lo & 1u) << 3);
}
__host__ __device__ constexpr unsigned Fmap(unsigned x) {
  return (x & 0xF00u) | ((x & 0xFu) << 4) | (((x >> 4) & 0xFu) ^ Qmap(x & 0xFu));
}

// DPP lane permutes (VALU): 0xB1 quad xor1, 0x4E quad xor2, 0x128 row_ror:8
template<int CTRL>
__device__ __forceinline__ float dppf(float x) {
  return __int_as_float(__builtin_amdgcn_update_dpp(
      0, __float_as_int(x), CTRL, 0xF, 0xF, true));
}
// ds_swizzle lane-xor (LDS pipe, no barrier): 0x101F = xor4 (init q5 only)
template<int PAT>
__device__ __forceinline__ float swzf(float x) {
  return __int_as_float(__builtin_amdgcn_ds_swizzle(__float_as_int(x), PAT));
}

#define FOR16(M) M(0) M(1) M(2) M(3) M(4) M(5) M(6) M(7) M(8) M(9) M(10) \
  M(11) M(12) M(13) M(14) M(15)

// packed shear pair-rotation (uses v2f locals kv, nkv in scope):
//   pi' = pi - k*pj ; pj' = pj + k*pi   (scalar c deferred to per-layer C)
#define ROT(i, j) {                                          \
    const v2f ti = p##i, tj = p##j;                          \
    p##i = __builtin_elementwise_fma(nkv, tj, ti);           \
    p##j = __builtin_elementwise_fma(kv,  ti, tj); }

#define GM8 ROT(0,8) ROT(1,9) ROT(2,10) ROT(3,11) ROT(4,12) ROT(5,13) \
  ROT(6,14) ROT(7,15)
#define GM4 ROT(0,4) ROT(1,5) ROT(2,6) ROT(3,7) ROT(8,12) ROT(9,13) \
  ROT(10,14) ROT(11,15)
#define GM2 ROT(0,2) ROT(1,3) ROT(4,6) ROT(5,7) ROT(8,10) ROT(9,11) \
  ROT(12,14) ROT(13,15)
#define GM1 ROT(0,1) ROT(2,3) ROT(4,5) ROT(6,7) ROT(8,9) ROT(10,11) \
  ROT(12,13) ROT(14,15)

// broadcast k for (layer l, gate g) from the per-wave trig table:
// reg = g&3 (literal), lane = l + 16*(g>>2) (uniform SGPR)
#define GETK(g) \
  const float kG = __int_as_float(__builtin_amdgcn_readlane( \
      __float_as_int(vkg[(g) & 3]), l + (((g) >> 2) << 4)));

__global__ __launch_bounds__(256)
void qnn_sim(const float* __restrict__ zr, const float* __restrict__ zi,
             const float* __restrict__ thetas, const int* __restrict__ y,
             float* __restrict__ out) {
  __shared__ v2f buf2[DIM];  // 32 KB: (re,im) per amp, slot = F(amp)
  const int b = blockIdx.x;
  const int t = threadIdx.x;  // 0..255

  // layer-invariant bases under F
  const int w1b = (int)((((unsigned)t & 0xF0u) << 4) | ((unsigned)t & 0xFu)); // F(t<<4)
  const int r1b = (int)Fmap((unsigned)t);                                      // F(t)
  const int Gt  = ((t << 4) ^ (t << 3)) & 0xFFF;                               // G(t<<4)
  const int r2b = (int)Fmap((unsigned)Gt);                                     // F(G(t<<4))

  // hoisted per-amp addresses (layer-invariant): W1 and R2-primary
#define MKADDR(i) \
  const int w1a##i = w1b ^ (int)Fmap((unsigned)i); \
  const int r2a##i = r2b ^ (int)Fmap(gperm((unsigned)i));
  FOR16(MKADDR)
#undef MKADDR

  v2f p0,p1,p2,p3,p4,p5,p6,p7,p8,p9,p10,p11,p12,p13,p14,p15;
  {
    const float4* zr4 = (const float4*)(zr + (size_t)b * DIM + (t << 4));
    const float4* zi4 = (const float4*)(zi + (size_t)b * DIM + (t << 4));
    const float4 a0 = zr4[0], a1 = zr4[1], a2 = zr4[2], a3 = zr4[3];
    const float4 b0 = zi4[0], b1 = zi4[1], b2 = zi4[2], b3 = zi4[3];
    p0  = (v2f){a0.x, b0.x}; p1  = (v2f){a0.y, b0.y};
    p2  = (v2f){a0.z, b0.z}; p3  = (v2f){a0.w, b0.w};
    p4  = (v2f){a1.x, b1.x}; p5  = (v2f){a1.y, b1.y};
    p6  = (v2f){a1.z, b1.z}; p7  = (v2f){a1.w, b1.w};
    p8  = (v2f){a2.x, b2.x}; p9  = (v2f){a2.y, b2.y};
    p10 = (v2f){a2.z, b2.z}; p11 = (v2f){a2.w, b2.w};
    p12 = (v2f){a3.x, b3.x}; p13 = (v2f){a3.y, b3.y};
    p14 = (v2f){a3.z, b3.z}; p15 = (v2f){a3.w, b3.w};
  }

  // ---- per-wave trig table (once), 4 VGPRs:
  // lanes 0..47:  vkg[j] = tan(theta[lane&15][4*(lane>>4)+j] / 2)
  // lanes 48..63: vkg[0] = C_l = prod_{g=0..11} cos(th/2)   (layer = lane-48)
  float vkg[4];
  {
    const int lane = t & 63;
    if (lane < 48) {
      const int lsrc = lane & 15;          // source layer
      const int gb = (lane >> 4) << 2;     // gate group base: 0, 4, 8
#pragma unroll
      for (int j = 0; j < 4; ++j) {
        const float a = 0.5f * thetas[lsrc * 12 + gb + j];
        vkg[j] = sinf(a) / cosf(a);
      }
    } else {
      const int lsrc = lane - 48;
      float c = 1.f;
      for (int g = 0; g < 12; ++g) c *= cosf(0.5f * thetas[lsrc * 12 + g]);
      vkg[0] = c; vkg[1] = 0.f; vkg[2] = 0.f; vkg[3] = 0.f;
    }
  }

  // ---- layer-0 q5 (amp bit 6 = lane xor4), once, via ds_swizzle shear ----
  {
    const float k5 = __int_as_float(__builtin_amdgcn_readlane(
        __float_as_int(vkg[1]), 16));  // layer 0, gate 5: reg 1, lane 0+16
    const float sg5 = (t & 4) ? k5 : -k5;
    const v2f skv = {sg5, sg5};
#define SWG5(i) { v2f pr; pr.x = swzf<0x101F>(p##i.x); pr.y = swzf<0x101F>(p##i.y); \
    p##i = __builtin_elementwise_fma(skv, pr, p##i); }
    FOR16(SWG5)
#undef SWG5
  }

#pragma unroll 1
  for (int l = 0; l < NLAYERS; ++l) {
    // per-layer deferred cosine product
    const float CL = __int_as_float(__builtin_amdgcn_readlane(
        __float_as_int(vkg[0]), 48 + l));

    // ---- L1 register gates: q8..q11 (amp bits 3..0 -> masks 8,4,2,1) ----
    { GETK(8)  const v2f kv = {kG,kG}, nkv = {-kG,-kG}; GM8 }
    { GETK(9)  const v2f kv = {kG,kG}, nkv = {-kG,-kG}; GM4 }
    { GETK(10) const v2f kv = {kG,kG}, nkv = {-kG,-kG}; GM2 }
    { GETK(11) const v2f kv = {kG,kG}, nkv = {-kG,-kG}; GM1 }

    // ---- DPP gates: q7 (t0, xor1), q6 (t1, xor2), q4 (t3, row_ror:8) ----
    // (q5 was applied by the previous layer's R2 fold / the init pass)
    {
      GETK(7)
      const float sg7 = (t & 1) ? kG : -kG;
      const v2f skv = {sg7,sg7};
#define DPPG7(i) { v2f pr; pr.x = dppf<0xB1>(p##i.x); pr.y = dppf<0xB1>(p##i.y); \
      p##i = __builtin_elementwise_fma(skv, pr, p##i); }
      FOR16(DPPG7)
#undef DPPG7
    }
    {
      GETK(6)
      const float sg6 = (t & 2) ? kG : -kG;
      const v2f skv = {sg6,sg6};
#define DPPG6(i) { v2f pr; pr.x = dppf<0x4E>(p##i.x); pr.y = dppf<0x4E>(p##i.y); \
      p##i = __builtin_elementwise_fma(skv, pr, p##i); }
      FOR16(DPPG6)
#undef DPPG6
    }
    {
      GETK(4)
      const float sg4 = (t & 8) ? kG : -kG;
      const v2f skv = {sg4,sg4};
#define DPPG4(i) { v2f pr; pr.x = dppf<0x128>(p##i.x); pr.y = dppf<0x128>(p##i.y); \
      p##i = __builtin_elementwise_fma(skv, pr, p##i); }
      FOR16(DPPG4)
#undef DPPG4
    }

    // ---- trip 1: L1 -> L2 (b64, slot = F(amp)) ----
    __syncthreads();  // prev layer's R2 reads (incl. partners) done
#define W1P(i) buf2[w1a##i] = p##i;
    FOR16(W1P)
#undef W1P
    __syncthreads();
#define R1P(i) p##i = buf2[r1b + (i << 8)];
    FOR16(R1P)
#undef R1P

    // ---- L2 register gates: q0..q3 (amp bits 11..8 -> masks 8,4,2,1) ----
    { GETK(0) const v2f kv = {kG,kG}, nkv = {-kG,-kG}; GM8 }
    { GETK(1) const v2f kv = {kG,kG}, nkv = {-kG,-kG}; GM4 }
    { GETK(2) const v2f kv = {kG,kG}, nkv = {-kG,-kG}; GM2 }
    { GETK(3) const v2f kv = {kG,kG}, nkv = {-kG,-kG}; GM1 }

    // ---- per-layer deferred C scale ----
    {
      const v2f cv = {CL, CL};
#define SCL(i) p##i = cv * p##i;
      FOR16(SCL)
#undef SCL
    }

    // ---- trip 2: L2 -> L1 fused with CNOT-ring gather ----
    // NO barrier before W2: each thread writes exactly the addresses it
    // read in R1 (bijective per-thread sets -> no cross-thread hazard).
#define W2P(i) buf2[r1b + (i << 8)] = p##i;
    FOR16(W2P)
#undef W2P
    __syncthreads();
#define R2P(i) p##i = buf2[r2a##i];
    FOR16(R2P)
#undef R2P

    // ---- R2 partner-fold: apply NEXT layer's q5 (amp bit 6) ----
    // partner of post-perm amp y=(t<<4)|i is y^0x40 at slot primary^0x006;
    // sign from bit6(y) = t2. Protected by the next pre-W1 barrier.
    if (l < NLAYERS - 1) {
      const float k5n = __int_as_float(__builtin_amdgcn_readlane(
          __float_as_int(vkg[1]), (l + 1) + 16));  // layer l+1, gate 5
      const float sg5 = (t & 4) ? k5n : -k5n;
      const v2f skv = {sg5, sg5};
#define R2F(i) { const v2f pr = buf2[r2a##i ^ 6]; \
      p##i = __builtin_elementwise_fma(skv, pr, p##i); }
      FOR16(R2F)
#undef R2F
    }
  }

  // ---- Z expectations: wire w sign = amp bit (11-w) = t bit (7-w) ----
  float P = 0.f;
#define ACC(i) P = __builtin_fmaf(p##i.x, p##i.x, P); \
               P = __builtin_fmaf(p##i.y, p##i.y, P);
  FOR16(ACC)
#undef ACC
  float e0 = ((t >> 7) & 1) ? -P : P;
  float e1 = ((t >> 6) & 1) ? -P : P;
  float e2 = ((t >> 5) & 1) ? -P : P;
  float e3 = ((t >> 4) & 1) ? -P : P;
  float e4 = ((t >> 3) & 1) ? -P : P;
#pragma unroll
  for (int off = 32; off >= 1; off >>= 1) {
    e0 += __shfl_xor(e0, off);
    e1 += __shfl_xor(e1, off);
    e2 += __shfl_xor(e2, off);
    e3 += __shfl_xor(e3, off);
    e4 += __shfl_xor(e4, off);
  }
  float* bf = (float*)buf2;
  __syncthreads();  // last R2 reads done before buf reuse
  if ((t & 63) == 0) {
    const int w8 = (t >> 6) * 8;
    bf[w8 + 0] = e0; bf[w8 + 1] = e1; bf[w8 + 2] = e2;
    bf[w8 + 3] = e3; bf[w8 + 4] = e4;
  }
  __syncthreads();
  if (t == 0) {
    const float o0 = bf[0] + bf[8]  + bf[16] + bf[24];
    const float o1 = bf[1] + bf[9]  + bf[17] + bf[25];
    const float o2 = bf[2] + bf[10] + bf[18] + bf[26];
    const float o3 = bf[3] + bf[11] + bf[19] + bf[27];
    const float o4 = bf[4] + bf[12] + bf[20] + bf[28];
    float* op = out + 1 + (size_t)b * NCLASS;
    op[0] = o0; op[1] = o1; op[2] = o2; op[3] = o3; op[4] = o4;
    // fused NLL: loss contribution = (logsumexp(o) - o[y]) / BATCH
    const float m = fmaxf(fmaxf(fmaxf(o0, o1), fmaxf(o2, o3)), o4);
    const float sum = expf(o0 - m) + expf(o1 - m) + expf(o2 - m) +
                      expf(o3 - m) + expf(o4 - m);
    const int yb = y[b];
    const float oy = (yb == 0) ? o0 : (yb == 1) ? o1 : (yb == 2) ? o2
                   : (yb == 3) ? o3 : o4;
    const float nll = (m + logf(sum)) - oy;
    atomicAdd(out, nll * (1.0f / BATCH));
  }
}

extern "C" void kernel_launch(void* const* d_in, const int* in_sizes, int n_in,
                              void* d_out, int out_size, void* d_ws, size_t ws_size,
                              hipStream_t stream) {
  const float* zr = (const float*)d_in[0];
  const float* zi = (const float*)d_in[1];
  const float* th = (const float*)d_in[2];
  const int*   y  = (const int*)d_in[3];
  float* out = (float*)d_out;
  hipMemsetAsync(out, 0, sizeof(float), stream);  // zero loss accumulator
  qnn_sim<<<BATCH, 256, 0, stream>>>(zr, zi, th, y, out);
}

// Round 4
// 197.893 us; speedup vs baseline: 1.2935x; 1.0873x over previous
//
#include <hip/hip_runtime.h>
#include <math.h>

// QuantumNeuralNetwork: 12-qubit, 16-layer RY+CNOT-ring state-vector sim.
// Round 13: round-12 structure (256 thr/block, 16 amps/lane as float2, tan-
// factored shears, per-wave trig table + readlane broadcast, b64 LDS trips
// under bank-proven slot map F, 3 barriers/layer) with q5 converted to a pure
// DPP gate via a LANE-COORDINATE CHANGE, eliminating ALL per-layer LDS lane
// shuffles (round-12's partner-fold reads and their 8.1M conflict cycles, and
// the init ds_swizzle pass):
//   DPP offers lane-xor masks {1 (quad 0xB1), 2 (quad 0x4E), 7 (row_half_
//   mirror 0x141, 7-x = 7^x), 8 (row_ror:8 0x128)} - rank 4 over GF(2).
//   Redefine L1 holder map: thread t holds amps y with y[7:4] = n(t[3:0]),
//   n0=t0^t2, n1=t1^t2, n2=t2, n3=t3  (tn = t ^ 3*t2, bijective).
//   Gate->lane-mask: q7(bit4)->xor1, q6(bit5)->xor2, q5(bit6)->xor7 (DPP!),
//   q4(bit7)->xor8. Sign masks: sg7=t0^t2, sg6=t1^t2, sg5=t2, sg4=t3.
// DS issues/lane/layer: 80 -> 64 (the two-transpose floor), conflicts -> ~0.
// Bank re-checks (by hand): W1 slot[3:0] = n(t[3:0]) ^ Q(i): n bijective per
// 16-lane group ✓. R2 slot[3:0] from tn: (s3,s2,s1,s0) = (t3^t4, t2^t3,
// t0^t1^t2, t1^t2) - invertible ✓. R1/W2 unchanged (L2 map = identity).
// Z-sign bits 11..7 = {t7..t4, n3=t3} - unchanged ✓.
//
// Bank-proven slot map F (GF(2)-linear, bijective), verified rounds 6-12:
//   s[3:0] = x[7:4] ^ Q(x[3:0]),  s[7:4] = x[3:0],  s[11:8] = x[11:8]
//   Q: q0=n0^n3, q1=n1^n3, q2=n2, q3=n0   (invertible)
// Gate placement:
//   L1: amp=(tn<<4)|r. q8..q11 reg (masks 8,4,2,1); q7,q6,q5,q4 DPP.
//   trip1 -> L2: amp=(r<<8)|t. q0..q3 reg (masks 8,4,2,1)
//   trip2 -> L1 fused with CNOT-ring perm G(i)=i^(i>>1)^(i0?0xC00:0).

#define DIM     4096
#define NLAYERS 16
#define BATCH   2048
#define NCLASS  5

typedef float v2f __attribute__((ext_vector_type(2)));

__host__ __device__ constexpr unsigned gperm(unsigned i) {
  for (int q = 11; q >= 0; --q) {
    const unsigned cbit = 1u << (11 - q);
    const unsigned tbit = 1u << (11 - ((q + 1) % 12));
    if (i & cbit) i ^= tbit;
  }
  return i;
}
// Q and F: the bank-proven slot map (see header comment)
__host__ __device__ constexpr unsigned Qmap(unsigned lo) {
  return ((lo ^ (lo >> 3)) & 1u) | ((((lo >> 1) ^ (lo >> 3)) & 1u) << 1) |
         (((lo >> 2) & 1u) << 2) | ((lo & 1u) << 3);
}
__host__ __device__ constexpr unsigned Fmap(unsigned x) {
  return (x & 0xF00u) | ((x & 0xFu) << 4) | (((x >> 4) & 0xFu) ^ Qmap(x & 0xFu));
}

// DPP lane permutes (VALU): 0xB1 quad xor1, 0x4E quad xor2,
// 0x141 row_half_mirror (xor7), 0x128 row_ror:8 (xor8)
template<int CTRL>
__device__ __forceinline__ float dppf(float x) {
  return __int_as_float(__builtin_amdgcn_update_dpp(
      0, __float_as_int(x), CTRL, 0xF, 0xF, true));
}

#define FOR16(M) M(0) M(1) M(2) M(3) M(4) M(5) M(6) M(7) M(8) M(9) M(10) \
  M(11) M(12) M(13) M(14) M(15)

// packed shear pair-rotation (uses v2f locals kv, nkv in scope):
//   pi' = pi - k*pj ; pj' = pj + k*pi   (scalar c deferred to per-layer C)
#define ROT(i, j) {                                          \
    const v2f ti = p##i, tj = p##j;                          \
    p##i = __builtin_elementwise_fma(nkv, tj, ti);           \
    p##j = __builtin_elementwise_fma(kv,  ti, tj); }

#define GM8 ROT(0,8) ROT(1,9) ROT(2,10) ROT(3,11) ROT(4,12) ROT(5,13) \
  ROT(6,14) ROT(7,15)
#define GM4 ROT(0,4) ROT(1,5) ROT(2,6) ROT(3,7) ROT(8,12) ROT(9,13) \
  ROT(10,14) ROT(11,15)
#define GM2 ROT(0,2) ROT(1,3) ROT(4,6) ROT(5,7) ROT(8,10) ROT(9,11) \
  ROT(12,14) ROT(13,15)
#define GM1 ROT(0,1) ROT(2,3) ROT(4,5) ROT(6,7) ROT(8,9) ROT(10,11) \
  ROT(12,13) ROT(14,15)

// broadcast k for (layer l, gate g) from the per-wave trig table:
// reg = g&3 (literal), lane = l + 16*(g>>2) (uniform SGPR)
#define GETK(g) \
  const float kG = __int_as_float(__builtin_amdgcn_readlane( \
      __float_as_int(vkg[(g) & 3]), l + (((g) >> 2) << 4)));

// DPP shear gate: partner = dpp<CTRL>(p), p += sg * partner
#define DPPGATE(CTRL, SG) { \
    const v2f skv = {SG, SG}; \
    _Pragma("nounroll") \
    { } \
  }

__global__ __launch_bounds__(256)
void qnn_sim(const float* __restrict__ zr, const float* __restrict__ zi,
             const float* __restrict__ thetas, const int* __restrict__ y,
             float* __restrict__ out) {
  __shared__ v2f buf2[DIM];  // 32 KB: (re,im) per amp, slot = F(amp)
  const int b = blockIdx.x;
  const int t = threadIdx.x;  // 0..255

  // lane-coordinate change: tn = t ^ 3*t2 (flips t1,t0 when t2 set)
  const int tn = t ^ (((t >> 2) & 1) * 3);

  // layer-invariant bases under F (L1 holder map uses tn; L2 uses t)
  const int w1b = ((t & 0xF0) << 4) | (tn & 0xF);                 // F(tn<<4)
  const int r1b = (int)Fmap((unsigned)t);                         // F(t)
  const int Gtn = ((tn << 4) ^ (tn << 3)) & 0xFFF;                // G(tn<<4)
  const int r2b = (int)Fmap((unsigned)Gtn);                       // F(G(tn<<4))

  // hoisted per-amp addresses (layer-invariant): W1 and R2
#define MKADDR(i) \
  const int w1a##i = w1b ^ (int)Fmap((unsigned)i); \
  const int r2a##i = r2b ^ (int)Fmap(gperm((unsigned)i));
  FOR16(MKADDR)
#undef MKADDR

  // DPP gate sign masks under the new lane map
  const bool m7 = ((t ^ (t >> 2)) & 1) != 0;         // amp bit4 = t0^t2
  const bool m6 = (((t >> 1) ^ (t >> 2)) & 1) != 0;  // amp bit5 = t1^t2
  const bool m5 = ((t >> 2) & 1) != 0;               // amp bit6 = t2
  const bool m4 = ((t >> 3) & 1) != 0;               // amp bit7 = t3

  v2f p0,p1,p2,p3,p4,p5,p6,p7,p8,p9,p10,p11,p12,p13,p14,p15;
  {
    const float4* zr4 = (const float4*)(zr + (size_t)b * DIM + (tn << 4));
    const float4* zi4 = (const float4*)(zi + (size_t)b * DIM + (tn << 4));
    const float4 a0 = zr4[0], a1 = zr4[1], a2 = zr4[2], a3 = zr4[3];
    const float4 b0 = zi4[0], b1 = zi4[1], b2 = zi4[2], b3 = zi4[3];
    p0  = (v2f){a0.x, b0.x}; p1  = (v2f){a0.y, b0.y};
    p2  = (v2f){a0.z, b0.z}; p3  = (v2f){a0.w, b0.w};
    p4  = (v2f){a1.x, b1.x}; p5  = (v2f){a1.y, b1.y};
    p6  = (v2f){a1.z, b1.z}; p7  = (v2f){a1.w, b1.w};
    p8  = (v2f){a2.x, b2.x}; p9  = (v2f){a2.y, b2.y};
    p10 = (v2f){a2.z, b2.z}; p11 = (v2f){a2.w, b2.w};
    p12 = (v2f){a3.x, b3.x}; p13 = (v2f){a3.y, b3.y};
    p14 = (v2f){a3.z, b3.z}; p15 = (v2f){a3.w, b3.w};
  }

  // ---- per-wave trig table (once), 4 VGPRs:
  // lanes 0..47:  vkg[j] = tan(theta[lane&15][4*(lane>>4)+j] / 2)
  // lanes 48..63: vkg[0] = C_l = prod_{g=0..11} cos(th/2)   (layer = lane-48)
  float vkg[4];
  {
    const int lane = t & 63;
    if (lane < 48) {
      const int lsrc = lane & 15;          // source layer
      const int gb = (lane >> 4) << 2;     // gate group base: 0, 4, 8
#pragma unroll
      for (int j = 0; j < 4; ++j) {
        const float a = 0.5f * thetas[lsrc * 12 + gb + j];
        vkg[j] = sinf(a) / cosf(a);
      }
    } else {
      const int lsrc = lane - 48;
      float c = 1.f;
      for (int g = 0; g < 12; ++g) c *= cosf(0.5f * thetas[lsrc * 12 + g]);
      vkg[0] = c; vkg[1] = 0.f; vkg[2] = 0.f; vkg[3] = 0.f;
    }
  }

#pragma unroll 1
  for (int l = 0; l < NLAYERS; ++l) {
    // per-layer deferred cosine product
    const float CL = __int_as_float(__builtin_amdgcn_readlane(
        __float_as_int(vkg[0]), 48 + l));

    // ---- L1 register gates: q8..q11 (amp bits 3..0 -> masks 8,4,2,1) ----
    { GETK(8)  const v2f kv = {kG,kG}, nkv = {-kG,-kG}; GM8 }
    { GETK(9)  const v2f kv = {kG,kG}, nkv = {-kG,-kG}; GM4 }
    { GETK(10) const v2f kv = {kG,kG}, nkv = {-kG,-kG}; GM2 }
    { GETK(11) const v2f kv = {kG,kG}, nkv = {-kG,-kG}; GM1 }

    // ---- DPP gates: q7 (xor1), q6 (xor2), q5 (xor7), q4 (xor8) ----
    {
      GETK(7)
      const float sg = m7 ? kG : -kG;
      const v2f skv = {sg,sg};
#define DPPG(i) { v2f pr; pr.x = dppf<0xB1>(p##i.x); pr.y = dppf<0xB1>(p##i.y); \
      p##i = __builtin_elementwise_fma(skv, pr, p##i); }
      FOR16(DPPG)
#undef DPPG
    }
    {
      GETK(6)
      const float sg = m6 ? kG : -kG;
      const v2f skv = {sg,sg};
#define DPPG(i) { v2f pr; pr.x = dppf<0x4E>(p##i.x); pr.y = dppf<0x4E>(p##i.y); \
      p##i = __builtin_elementwise_fma(skv, pr, p##i); }
      FOR16(DPPG)
#undef DPPG
    }
    {
      GETK(5)
      const float sg = m5 ? kG : -kG;
      const v2f skv = {sg,sg};
#define DPPG(i) { v2f pr; pr.x = dppf<0x141>(p##i.x); pr.y = dppf<0x141>(p##i.y); \
      p##i = __builtin_elementwise_fma(skv, pr, p##i); }
      FOR16(DPPG)
#undef DPPG
    }
    {
      GETK(4)
      const float sg = m4 ? kG : -kG;
      const v2f skv = {sg,sg};
#define DPPG(i) { v2f pr; pr.x = dppf<0x128>(p##i.x); pr.y = dppf<0x128>(p##i.y); \
      p##i = __builtin_elementwise_fma(skv, pr, p##i); }
      FOR16(DPPG)
#undef DPPG
    }

    // ---- trip 1: L1 -> L2 (b64, slot = F(amp)) ----
    __syncthreads();  // prev layer's R2 reads done
#define W1P(i) buf2[w1a##i] = p##i;
    FOR16(W1P)
#undef W1P
    __syncthreads();
#define R1P(i) p##i = buf2[r1b + (i << 8)];
    FOR16(R1P)
#undef R1P

    // ---- L2 register gates: q0..q3 (amp bits 11..8 -> masks 8,4,2,1) ----
    { GETK(0) const v2f kv = {kG,kG}, nkv = {-kG,-kG}; GM8 }
    { GETK(1) const v2f kv = {kG,kG}, nkv = {-kG,-kG}; GM4 }
    { GETK(2) const v2f kv = {kG,kG}, nkv = {-kG,-kG}; GM2 }
    { GETK(3) const v2f kv = {kG,kG}, nkv = {-kG,-kG}; GM1 }

    // ---- per-layer deferred C scale ----
    {
      const v2f cv = {CL, CL};
#define SCL(i) p##i = cv * p##i;
      FOR16(SCL)
#undef SCL
    }

    // ---- trip 2: L2 -> L1 fused with CNOT-ring gather ----
    // NO barrier before W2: each thread writes exactly the addresses it
    // read in R1 (bijective per-thread sets -> no cross-thread hazard).
#define W2P(i) buf2[r1b + (i << 8)] = p##i;
    FOR16(W2P)
#undef W2P
    __syncthreads();
#define R2P(i) p##i = buf2[r2a##i];
    FOR16(R2P)
#undef R2P
  }

  // ---- Z expectations: wire w sign = amp bit (11-w) ----
  // bits 11..8 = t[7:4]; bit 7 = n3 = t3 -> same t-bit mapping as before.
  float P = 0.f;
#define ACC(i) P = __builtin_fmaf(p##i.x, p##i.x, P); \
               P = __builtin_fmaf(p##i.y, p##i.y, P);
  FOR16(ACC)
#undef ACC
  float e0 = ((t >> 7) & 1) ? -P : P;
  float e1 = ((t >> 6) & 1) ? -P : P;
  float e2 = ((t >> 5) & 1) ? -P : P;
  float e3 = ((t >> 4) & 1) ? -P : P;
  float e4 = ((t >> 3) & 1) ? -P : P;
#pragma unroll
  for (int off = 32; off >= 1; off >>= 1) {
    e0 += __shfl_xor(e0, off);
    e1 += __shfl_xor(e1, off);
    e2 += __shfl_xor(e2, off);
    e3 += __shfl_xor(e3, off);
    e4 += __shfl_xor(e4, off);
  }
  float* bf = (float*)buf2;
  __syncthreads();  // last R2 reads done before buf reuse
  if ((t & 63) == 0) {
    const int w8 = (t >> 6) * 8;
    bf[w8 + 0] = e0; bf[w8 + 1] = e1; bf[w8 + 2] = e2;
    bf[w8 + 3] = e3; bf[w8 + 4] = e4;
  }
  __syncthreads();
  if (t == 0) {
    const float o0 = bf[0] + bf[8]  + bf[16] + bf[24];
    const float o1 = bf[1] + bf[9]  + bf[17] + bf[25];
    const float o2 = bf[2] + bf[10] + bf[18] + bf[26];
    const float o3 = bf[3] + bf[11] + bf[19] + bf[27];
    const float o4 = bf[4] + bf[12] + bf[20] + bf[28];
    float* op = out + 1 + (size_t)b * NCLASS;
    op[0] = o0; op[1] = o1; op[2] = o2; op[3] = o3; op[4] = o4;
    // fused NLL: loss contribution = (logsumexp(o) - o[y]) / BATCH
    const float m = fmaxf(fmaxf(fmaxf(o0, o1), fmaxf(o2, o3)), o4);
    const float sum = expf(o0 - m) + expf(o1 - m) + expf(o2 - m) +
                      expf(o3 - m) + expf(o4 - m);
    const int yb = y[b];
    const float oy = (yb == 0) ? o0 : (yb == 1) ? o1 : (yb == 2) ? o2
                   : (yb == 3) ? o3 : o4;
    const float nll = (m + logf(sum)) - oy;
    atomicAdd(out, nll * (1.0f / BATCH));
  }
}

extern "C" void kernel_launch(void* const* d_in, const int* in_sizes, int n_in,
                              void* d_out, int out_size, void* d_ws, size_t ws_size,
                              hipStream_t stream) {
  const float* zr = (const float*)d_in[0];
  const float* zi = (const float*)d_in[1];
  const float* th = (const float*)d_in[2];
  const int*   y  = (const int*)d_in[3];
  float* out = (float*)d_out;
  hipMemsetAsync(out, 0, sizeof(float), stream);  // zero loss accumulator
  qnn_sim<<<BATCH, 256, 0, stream>>>(zr, zi, th, y, out);
}

// Round 5
// 192.503 us; speedup vs baseline: 1.3297x; 1.0280x over previous
//
#include <hip/hip_runtime.h>
#include <math.h>

// QuantumNeuralNetwork: 12-qubit, 16-layer RY+CNOT-ring state-vector sim.
// Round 14: round-13 structure (256 thr/block, 16 amps/lane as float2, tan-
// factored shears, per-wave trig table + readlane broadcast, all-DPP lane
// gates via tn = t ^ 3*t2 coordinate change, b64 LDS trips under slot map F,
// 3 barriers/layer) with two VALU trims:
// 1) DPP gates fused to v_fmac_f32_dpp (inline asm): p += sg*dpp_xor(p) is
//    ONE VOP2-DPP instr per component (2/amp) vs mov_dpp x2 + pk_fma (3/amp).
//    Hazard discipline: each gate = 2 asm blocks of 16 fmacs (8 amps); each
//    block opens with s_nop 1 (2 wait states) covering any producer scheduled
//    at distance -1/-2 before the block; within a block all 16 regs are
//    distinct (each fmac reads dpp(own old) and writes own), so no intra-
//    block hazard; across blocks distance >= 17 instructions.
// 2) C-scale deferred GLOBALLY: per-layer 16 pk_mul + readlane dropped;
//    P *= (prod_l C_l)^2 once at the end. Bounds: true norm = 1 so
//    |amp_raw| <= (prodC)^-1 ~ 6e14, |amp|^2 <= 4e29 < fp32 max; (prodC)^2
//    >= ~4e-30 > min normal. Relative rounding unchanged (scale-free fp32).
// VALU issues/lane/layer: ~349 -> ~268. Bank conflicts (4.19M) understood as
// b64-structural (~0.5 cyc/access, 6.8 us/CU total) - not worth chasing.
//
// Slot map F (GF(2)-linear, bijective), verified rounds 6-13:
//   s[3:0] = x[7:4] ^ Q(x[3:0]),  s[7:4] = x[3:0],  s[11:8] = x[11:8]
// Lane map (round 13): thread t holds amps y, y[7:4] = n(t[3:0]),
//   n0=t0^t2, n1=t1^t2, n2=t2, n3=t3 (tn = t ^ 3*t2). Gate->DPP:
//   q7(bit4)->xor1 quad_perm:[1,0,3,2], q6(bit5)->xor2 quad_perm:[2,3,0,1],
//   q5(bit6)->xor7 row_half_mirror,     q4(bit7)->xor8 row_ror:8.
//   Signs: sg7=t0^t2, sg6=t1^t2, sg5=t2, sg4=t3.
// Gate placement:
//   L1: amp=(tn<<4)|r. q8..q11 reg (masks 8,4,2,1); q7,q6,q5,q4 DPP-fmac.
//   trip1 -> L2: amp=(r<<8)|t. q0..q3 reg (masks 8,4,2,1)
//   trip2 -> L1 fused with CNOT-ring perm G(i)=i^(i>>1)^(i0?0xC00:0).

#define DIM     4096
#define NLAYERS 16
#define BATCH   2048
#define NCLASS  5

typedef float v2f __attribute__((ext_vector_type(2)));

__host__ __device__ constexpr unsigned gperm(unsigned i) {
  for (int q = 11; q >= 0; --q) {
    const unsigned cbit = 1u << (11 - q);
    const unsigned tbit = 1u << (11 - ((q + 1) % 12));
    if (i & cbit) i ^= tbit;
  }
  return i;
}
// Q and F: the slot map (see header comment)
__host__ __device__ constexpr unsigned Qmap(unsigned lo) {
  return ((lo ^ (lo >> 3)) & 1u) | ((((lo >> 1) ^ (lo >> 3)) & 1u) << 1) |
         (((lo >> 2) & 1u) << 2) | ((lo & 1u) << 3);
}
__host__ __device__ constexpr unsigned Fmap(unsigned x) {
  return (x & 0xF00u) | ((x & 0xFu) << 4) | (((x >> 4) & 0xFu) ^ Qmap(x & 0xFu));
}

#define FOR16(M) M(0) M(1) M(2) M(3) M(4) M(5) M(6) M(7) M(8) M(9) M(10) \
  M(11) M(12) M(13) M(14) M(15)

// packed shear pair-rotation (uses v2f locals kv, nkv in scope):
//   pi' = pi - k*pj ; pj' = pj + k*pi   (scalar c deferred globally)
#define ROT(i, j) {                                          \
    const v2f ti = p##i, tj = p##j;                          \
    p##i = __builtin_elementwise_fma(nkv, tj, ti);           \
    p##j = __builtin_elementwise_fma(kv,  ti, tj); }

#define GM8 ROT(0,8) ROT(1,9) ROT(2,10) ROT(3,11) ROT(4,12) ROT(5,13) \
  ROT(6,14) ROT(7,15)
#define GM4 ROT(0,4) ROT(1,5) ROT(2,6) ROT(3,7) ROT(8,12) ROT(9,13) \
  ROT(10,14) ROT(11,15)
#define GM2 ROT(0,2) ROT(1,3) ROT(4,6) ROT(5,7) ROT(8,10) ROT(9,11) \
  ROT(12,14) ROT(13,15)
#define GM1 ROT(0,1) ROT(2,3) ROT(4,5) ROT(6,7) ROT(8,9) ROT(10,11) \
  ROT(12,13) ROT(14,15)

// broadcast k for (layer l, gate g) from the per-wave trig table:
// reg = g&3 (literal), lane = l + 16*(g>>2) (uniform SGPR)
#define GETK(g) \
  const float kG = __int_as_float(__builtin_amdgcn_readlane( \
      __float_as_int(vkg[(g) & 3]), l + (((g) >> 2) << 4)));

// fused DPP shear on 8 amps (16 scalar components): p += sg * dpp_xor(p).
// One v_fmac_f32_dpp per component; leading s_nop 1 = 2 wait states for the
// VALU-write -> DPP-read hazard vs any producer at distance -1/-2.
#define DPP8(CTRL, iA,iB,iC,iD,iE,iF,iG,iH) { \
    float a0 = p##iA.x, a1 = p##iA.y, a2 = p##iB.x, a3 = p##iB.y, \
          a4 = p##iC.x, a5 = p##iC.y, a6 = p##iD.x, a7 = p##iD.y, \
          a8 = p##iE.x, a9 = p##iE.y, a10 = p##iF.x, a11 = p##iF.y, \
          a12 = p##iG.x, a13 = p##iG.y, a14 = p##iH.x, a15 = p##iH.y; \
    asm("s_nop 1\n\t" \
        "v_fmac_f32_dpp %0, %0, %16 " CTRL "\n\t" \
        "v_fmac_f32_dpp %1, %1, %16 " CTRL "\n\t" \
        "v_fmac_f32_dpp %2, %2, %16 " CTRL "\n\t" \
        "v_fmac_f32_dpp %3, %3, %16 " CTRL "\n\t" \
        "v_fmac_f32_dpp %4, %4, %16 " CTRL "\n\t" \
        "v_fmac_f32_dpp %5, %5, %16 " CTRL "\n\t" \
        "v_fmac_f32_dpp %6, %6, %16 " CTRL "\n\t" \
        "v_fmac_f32_dpp %7, %7, %16 " CTRL "\n\t" \
        "v_fmac_f32_dpp %8, %8, %16 " CTRL "\n\t" \
        "v_fmac_f32_dpp %9, %9, %16 " CTRL "\n\t" \
        "v_fmac_f32_dpp %10, %10, %16 " CTRL "\n\t" \
        "v_fmac_f32_dpp %11, %11, %16 " CTRL "\n\t" \
        "v_fmac_f32_dpp %12, %12, %16 " CTRL "\n\t" \
        "v_fmac_f32_dpp %13, %13, %16 " CTRL "\n\t" \
        "v_fmac_f32_dpp %14, %14, %16 " CTRL "\n\t" \
        "v_fmac_f32_dpp %15, %15, %16 " CTRL \
        : "+v"(a0), "+v"(a1), "+v"(a2), "+v"(a3), "+v"(a4), "+v"(a5), \
          "+v"(a6), "+v"(a7), "+v"(a8), "+v"(a9), "+v"(a10), "+v"(a11), \
          "+v"(a12), "+v"(a13), "+v"(a14), "+v"(a15) \
        : "v"(sg)); \
    p##iA.x = a0;  p##iA.y = a1;  p##iB.x = a2;  p##iB.y = a3; \
    p##iC.x = a4;  p##iC.y = a5;  p##iD.x = a6;  p##iD.y = a7; \
    p##iE.x = a8;  p##iE.y = a9;  p##iF.x = a10; p##iF.y = a11; \
    p##iG.x = a12; p##iG.y = a13; p##iH.x = a14; p##iH.y = a15; }

#define DPPGATE(CTRL) \
  DPP8(CTRL, 0,1,2,3,4,5,6,7) DPP8(CTRL, 8,9,10,11,12,13,14,15)

__global__ __launch_bounds__(256)
void qnn_sim(const float* __restrict__ zr, const float* __restrict__ zi,
             const float* __restrict__ thetas, const int* __restrict__ y,
             float* __restrict__ out) {
  __shared__ v2f buf2[DIM];  // 32 KB: (re,im) per amp, slot = F(amp)
  const int b = blockIdx.x;
  const int t = threadIdx.x;  // 0..255

  // lane-coordinate change: tn = t ^ 3*t2 (flips t1,t0 when t2 set)
  const int tn = t ^ (((t >> 2) & 1) * 3);

  // layer-invariant bases under F (L1 holder map uses tn; L2 uses t)
  const int w1b = ((t & 0xF0) << 4) | (tn & 0xF);                 // F(tn<<4)
  const int r1b = (int)Fmap((unsigned)t);                         // F(t)
  const int Gtn = ((tn << 4) ^ (tn << 3)) & 0xFFF;                // G(tn<<4)
  const int r2b = (int)Fmap((unsigned)Gtn);                       // F(G(tn<<4))

  // hoisted per-amp addresses (layer-invariant): W1 and R2
#define MKADDR(i) \
  const int w1a##i = w1b ^ (int)Fmap((unsigned)i); \
  const int r2a##i = r2b ^ (int)Fmap(gperm((unsigned)i));
  FOR16(MKADDR)
#undef MKADDR

  // DPP gate sign masks under the lane map
  const bool m7 = ((t ^ (t >> 2)) & 1) != 0;         // amp bit4 = t0^t2
  const bool m6 = (((t >> 1) ^ (t >> 2)) & 1) != 0;  // amp bit5 = t1^t2
  const bool m5 = ((t >> 2) & 1) != 0;               // amp bit6 = t2
  const bool m4 = ((t >> 3) & 1) != 0;               // amp bit7 = t3

  v2f p0,p1,p2,p3,p4,p5,p6,p7,p8,p9,p10,p11,p12,p13,p14,p15;
  {
    const float4* zr4 = (const float4*)(zr + (size_t)b * DIM + (tn << 4));
    const float4* zi4 = (const float4*)(zi + (size_t)b * DIM + (tn << 4));
    const float4 a0 = zr4[0], a1 = zr4[1], a2 = zr4[2], a3 = zr4[3];
    const float4 b0 = zi4[0], b1 = zi4[1], b2 = zi4[2], b3 = zi4[3];
    p0  = (v2f){a0.x, b0.x}; p1  = (v2f){a0.y, b0.y};
    p2  = (v2f){a0.z, b0.z}; p3  = (v2f){a0.w, b0.w};
    p4  = (v2f){a1.x, b1.x}; p5  = (v2f){a1.y, b1.y};
    p6  = (v2f){a1.z, b1.z}; p7  = (v2f){a1.w, b1.w};
    p8  = (v2f){a2.x, b2.x}; p9  = (v2f){a2.y, b2.y};
    p10 = (v2f){a2.z, b2.z}; p11 = (v2f){a2.w, b2.w};
    p12 = (v2f){a3.x, b3.x}; p13 = (v2f){a3.y, b3.y};
    p14 = (v2f){a3.z, b3.z}; p15 = (v2f){a3.w, b3.w};
  }

  // ---- per-wave trig table (once), 4 VGPRs:
  // lanes 0..47:  vkg[j] = tan(theta[lane&15][4*(lane>>4)+j] / 2)
  // lanes 48..63: vkg[0] = C_l = prod_{g=0..11} cos(th/2)   (layer = lane-48)
  float vkg[4];
  {
    const int lane = t & 63;
    if (lane < 48) {
      const int lsrc = lane & 15;          // source layer
      const int gb = (lane >> 4) << 2;     // gate group base: 0, 4, 8
#pragma unroll
      for (int j = 0; j < 4; ++j) {
        const float a = 0.5f * thetas[lsrc * 12 + gb + j];
        vkg[j] = sinf(a) / cosf(a);
      }
    } else {
      const int lsrc = lane - 48;
      float c = 1.f;
      for (int g = 0; g < 12; ++g) c *= cosf(0.5f * thetas[lsrc * 12 + g]);
      vkg[0] = c; vkg[1] = 0.f; vkg[2] = 0.f; vkg[3] = 0.f;
    }
  }
  // global deferred scale: (prod_l C_l)^2, applied to P at the end
  float pcl = 1.f;
#pragma unroll
  for (int l2 = 0; l2 < NLAYERS; ++l2)
    pcl *= __int_as_float(__builtin_amdgcn_readlane(
        __float_as_int(vkg[0]), 48 + l2));
  const float pc2 = pcl * pcl;

#pragma unroll 1
  for (int l = 0; l < NLAYERS; ++l) {
    // ---- L1 register gates: q8..q11 (amp bits 3..0 -> masks 8,4,2,1) ----
    { GETK(8)  const v2f kv = {kG,kG}, nkv = {-kG,-kG}; GM8 }
    { GETK(9)  const v2f kv = {kG,kG}, nkv = {-kG,-kG}; GM4 }
    { GETK(10) const v2f kv = {kG,kG}, nkv = {-kG,-kG}; GM2 }
    { GETK(11) const v2f kv = {kG,kG}, nkv = {-kG,-kG}; GM1 }

    // ---- DPP-fmac gates: q7 (xor1), q6 (xor2), q5 (xor7), q4 (xor8) ----
    { GETK(7) const float sg = m7 ? kG : -kG;
      DPPGATE("quad_perm:[1,0,3,2] row_mask:0xf bank_mask:0xf") }
    { GETK(6) const float sg = m6 ? kG : -kG;
      DPPGATE("quad_perm:[2,3,0,1] row_mask:0xf bank_mask:0xf") }
    { GETK(5) const float sg = m5 ? kG : -kG;
      DPPGATE("row_half_mirror row_mask:0xf bank_mask:0xf") }
    { GETK(4) const float sg = m4 ? kG : -kG;
      DPPGATE("row_ror:8 row_mask:0xf bank_mask:0xf") }

    // ---- trip 1: L1 -> L2 (b64, slot = F(amp)) ----
    __syncthreads();  // prev layer's R2 reads done
#define W1P(i) buf2[w1a##i] = p##i;
    FOR16(W1P)
#undef W1P
    __syncthreads();
#define R1P(i) p##i = buf2[r1b + (i << 8)];
    FOR16(R1P)
#undef R1P

    // ---- L2 register gates: q0..q3 (amp bits 11..8 -> masks 8,4,2,1) ----
    { GETK(0) const v2f kv = {kG,kG}, nkv = {-kG,-kG}; GM8 }
    { GETK(1) const v2f kv = {kG,kG}, nkv = {-kG,-kG}; GM4 }
    { GETK(2) const v2f kv = {kG,kG}, nkv = {-kG,-kG}; GM2 }
    { GETK(3) const v2f kv = {kG,kG}, nkv = {-kG,-kG}; GM1 }

    // ---- trip 2: L2 -> L1 fused with CNOT-ring gather ----
    // NO barrier before W2: each thread writes exactly the addresses it
    // read in R1 (bijective per-thread sets -> no cross-thread hazard).
#define W2P(i) buf2[r1b + (i << 8)] = p##i;
    FOR16(W2P)
#undef W2P
    __syncthreads();
#define R2P(i) p##i = buf2[r2a##i];
    FOR16(R2P)
#undef R2P
  }

  // ---- Z expectations: wire w sign = amp bit (11-w) ----
  // bits 11..8 = t[7:4]; bit 7 = n3 = t3 -> same t-bit mapping as before.
  float P = 0.f;
#define ACC(i) P = __builtin_fmaf(p##i.x, p##i.x, P); \
               P = __builtin_fmaf(p##i.y, p##i.y, P);
  FOR16(ACC)
#undef ACC
  P *= pc2;  // global deferred (prod C)^2
  float e0 = ((t >> 7) & 1) ? -P : P;
  float e1 = ((t >> 6) & 1) ? -P : P;
  float e2 = ((t >> 5) & 1) ? -P : P;
  float e3 = ((t >> 4) & 1) ? -P : P;
  float e4 = ((t >> 3) & 1) ? -P : P;
#pragma unroll
  for (int off = 32; off >= 1; off >>= 1) {
    e0 += __shfl_xor(e0, off);
    e1 += __shfl_xor(e1, off);
    e2 += __shfl_xor(e2, off);
    e3 += __shfl_xor(e3, off);
    e4 += __shfl_xor(e4, off);
  }
  float* bf = (float*)buf2;
  __syncthreads();  // last R2 reads done before buf reuse
  if ((t & 63) == 0) {
    const int w8 = (t >> 6) * 8;
    bf[w8 + 0] = e0; bf[w8 + 1] = e1; bf[w8 + 2] = e2;
    bf[w8 + 3] = e3; bf[w8 + 4] = e4;
  }
  __syncthreads();
  if (t == 0) {
    const float o0 = bf[0] + bf[8]  + bf[16] + bf[24];
    const float o1 = bf[1] + bf[9]  + bf[17] + bf[25];
    const float o2 = bf[2] + bf[10] + bf[18] + bf[26];
    const float o3 = bf[3] + bf[11] + bf[19] + bf[27];
    const float o4 = bf[4] + bf[12] + bf[20] + bf[28];
    float* op = out + 1 + (size_t)b * NCLASS;
    op[0] = o0; op[1] = o1; op[2] = o2; op[3] = o3; op[4] = o4;
    // fused NLL: loss contribution = (logsumexp(o) - o[y]) / BATCH
    const float m = fmaxf(fmaxf(fmaxf(o0, o1), fmaxf(o2, o3)), o4);
    const float sum = expf(o0 - m) + expf(o1 - m) + expf(o2 - m) +
                      expf(o3 - m) + expf(o4 - m);
    const int yb = y[b];
    const float oy = (yb == 0) ? o0 : (yb == 1) ? o1 : (yb == 2) ? o2
                   : (yb == 3) ? o3 : o4;
    const float nll = (m + logf(sum)) - oy;
    atomicAdd(out, nll * (1.0f / BATCH));
  }
}

extern "C" void kernel_launch(void* const* d_in, const int* in_sizes, int n_in,
                              void* d_out, int out_size, void* d_ws, size_t ws_size,
                              hipStream_t stream) {
  const float* zr = (const float*)d_in[0];
  const float* zi = (const float*)d_in[1];
  const float* th = (const float*)d_in[2];
  const int*   y  = (const int*)d_in[3];
  float* out = (float*)d_out;
  hipMemsetAsync(out, 0, sizeof(float), stream);  // zero loss accumulator
  qnn_sim<<<BATCH, 256, 0, stream>>>(zr, zi, th, y, out);
}